// Round 14
// baseline (167.865 us; speedup 1.0000x reference)
//
#include <hip/hip_runtime.h>

#define CIN 512
#define COUT 512
#define HH 64
#define WW 64
#define BB 8
#define KTOT 4608   // 512*9

#define XPD 66                // padded spatial dim: index = coord+1, coord in -1..64
#define BUFSH (3 * 66 * 64)   // 12672 shorts per LDS buffer (3 rows x 66 slices x 64 ch)
#define ROWB (66 * 128)       // 8448 bytes per LDS input row

typedef __attribute__((ext_vector_type(8))) short short8;
typedef __attribute__((ext_vector_type(4))) float f32x4;

__device__ inline unsigned short f2bf(float f) {
    unsigned int u = __float_as_uint(f);
    u += 0x7FFFu + ((u >> 16) & 1u);   // round-to-nearest-even
    return (unsigned short)(u >> 16);
}

__device__ inline void gll16(const void* g, void* l) {
    __builtin_amdgcn_global_load_lds(
        (const __attribute__((address_space(1))) unsigned int*)g,
        (__attribute__((address_space(3))) unsigned int*)l, 16, 0, 0);
}

// ---------------- Phase -1: zero the halo ring of XTP ----------------
__global__ __launch_bounds__(256) void zring_kernel(unsigned short* __restrict__ xtp) {
    const int e = blockIdx.x * 256 + threadIdx.x;   // 520*256 >= 8*260*64
    if (e >= BB * 260 * 64) return;
    const int unit = e & 63;
    const int sa = e >> 6;           // 0..2079
    const int b = sa / 260;
    const int s = sa - b * 260;
    int yy, xx;
    if (s < 66)       { yy = 0;        xx = s; }
    else if (s < 132) { yy = 65;       xx = s - 66; }
    else if (s < 196) { yy = s - 131;  xx = 0; }     // rows 1..64
    else              { yy = s - 195;  xx = 65; }    // rows 1..64
    *(short8*)(xtp + ((size_t)(b * XPD + yy) * XPD + xx) * 512 + unit * 8) =
        (short8){0, 0, 0, 0, 0, 0, 0, 0};
}

// ------- Phase 0: x [b][i][y][x] fp32 * (1+style[b][i]) -> XTP [b][y+1][x+1][i] bf16 -------
__global__ __launch_bounds__(256) void xpose_kernel(const float* __restrict__ x,
                                                    const float* __restrict__ style,
                                                    unsigned short* __restrict__ xtp) {
    __shared__ float tile[32 * 65];
    __shared__ float sst[32];
    const int ic = blockIdx.x;   // 16 groups of 32 channels
    const int y  = blockIdx.y;
    const int b  = blockIdx.z;
    const int t  = threadIdx.x;
    if (t < 32) sst[t] = style[b * CIN + ic * 32 + t] + 1.0f;
#pragma unroll
    for (int it = 0; it < 2; ++it) {
        const int m  = it * 256 + t;        // 0..511 float4 loads
        const int ii = m >> 4, xq = m & 15;
        const float4 v = ((const float4*)x)[((size_t)(b * CIN + ic * 32 + ii) * HH + y) * 16 + xq];
        float* tp = &tile[ii * 65 + xq * 4];
        tp[0] = v.x; tp[1] = v.y; tp[2] = v.z; tp[3] = v.w;
    }
    __syncthreads();
    const int xx = t >> 2, ii8 = t & 3;     // 64 cols x 4 ch-octets
    short8 v8;
#pragma unroll
    for (int k = 0; k < 8; ++k)
        v8[k] = (short)f2bf(tile[(ii8 * 8 + k) * 65 + xx] * sst[ii8 * 8 + k]);
    *(short8*)(xtp + ((size_t)(b * XPD + y + 1) * XPD + (xx + 1)) * 512 + ic * 32 + ii8 * 8) = v8;
}

// ------- Phase 1 (fused): frag-pack w*c AND sigma_inv[b][o], one weight-row pass -------
__global__ __launch_bounds__(256) void wprep_kernel(const float* __restrict__ weight,
                                                    const float* __restrict__ style,
                                                    unsigned short* __restrict__ wpk,
                                                    float* __restrict__ siginv) {
    __shared__ float q[KTOT];
    __shared__ float sred[4][8];
    const int o = blockIdx.x;
    const int t = threadIdx.x;
    const float* wrow = weight + (size_t)o * KTOT;   // e = i*9+tap
    const float cst = 1.0f / sqrtf((float)KTOT);
#pragma unroll
    for (int it = 0; it < 18; ++it) {
        int e = it * 256 + t;
        q[e] = wrow[e] * cst;
    }
    __syncthreads();
    float acc[8] = {0.f, 0.f, 0.f, 0.f, 0.f, 0.f, 0.f, 0.f};
#pragma unroll
    for (int ii = 0; ii < 2; ++ii) {
        const int i = t * 2 + ii;
        float wsq = 0.f;
#pragma unroll
        for (int tap = 0; tap < 9; ++tap) {
            float v = q[i * 9 + tap];
            wsq += v * v;
        }
#pragma unroll
        for (int b = 0; b < 8; ++b) {
            float s = style[b * CIN + i] + 1.0f;
            acc[b] += wsq * s * s;
        }
    }
#pragma unroll
    for (int b = 0; b < 8; ++b) {
        float v = acc[b];
#pragma unroll
        for (int off = 32; off > 0; off >>= 1) v += __shfl_down(v, off, 64);
        if ((t & 63) == 0) sred[t >> 6][b] = v;
    }
    __syncthreads();
    if (t < 8) {
        const float S = sred[0][t] + sred[1][t] + sred[2][t] + sred[3][t];
        siginv[t * COUT + o] = rsqrtf(S + 1e-8f);
    }
    const int g = o >> 4, l15 = o & 15;
    for (int m = t; m < 576; m += 256) {   // m -> (c, tap, l4)
        int c   = m / 36;
        int rem = m - c * 36;
        int tap = rem >> 2;
        int l4  = rem & 3;
        short8 v;
#pragma unroll
        for (int e = 0; e < 8; ++e)
            v[e] = (short)f2bf(q[(c * 32 + l4 * 8 + e) * 9 + tap]);
        *(short8*)(wpk + ((((size_t)c * 9 + tap) * 32 + g) * 64 + l4 * 16 + l15) * 8) = v;
    }
}

// ---------------- Phase 2: implicit-GEMM conv, barrier-paced (8-phase-style) ----------
// Geometry = r8 (proven): 256 thr = 4 waves; tile 256 o x 1 row x 64 px; 3 blocks/CU;
// wave og = wid: 64 o x 64 px -> acc[4][4]; A af[3] 2-deep rotation, G linear.
// NEW: per phase {4 ds_read B + 4 A-loads + [s==0: STAGE] ; s_barrier ; lgkmcnt(0) ;
// setprio(1) ; 16 MFMA ; setprio(0) ; [s==17: vmcnt(8)] ; s_barrier}.
// vmcnt(8) preserves exactly the 2 newest A-prefetch sets across the ic boundary and
// drains all older VMEM (incl. the gll16 stage writes) -> raw barriers are safe.
__global__ __launch_bounds__(256, 3) void conv_kernel(const unsigned short* __restrict__ wpk,
                                                      const unsigned short* __restrict__ xtp,
                                                      const float* __restrict__ siginv,
                                                      const float* __restrict__ bias,
                                                      float* __restrict__ out) {
    __shared__ __align__(16) unsigned short xs[2 * BUFSH];   // 50688 B
    // XCD-aware decode: XCD k = bid&7 owns ob = k&1 (2.36 MB weight half, L2-hot)
    const int bid = blockIdx.x;
    const int k  = bid & 7;
    const int t  = bid >> 3;            // 0..127
    const int ob = k & 1;
    const int b  = (k >> 1) * 2 + (t >> 6);
    const int yb = t & 63;              // output row

    const int tid  = threadIdx.x;
    const int lane = tid & 63;
    const int wid_u = __builtin_amdgcn_readfirstlane(tid >> 6);   // wave-uniform -> SGPR
    const int l15 = lane & 15, l4 = lane >> 4;
    const int og = wid_u;               // 0..3, 64 o each
    const int g0 = ob * 16 + og * 4;    // o-frag base (frags of 16 o), scalar

    // ---- staging precompute: slices 0..197 (row = sl/66, col = sl%66), 128B each.
    const int up = lane & 7;
    const unsigned short* srcq[6];
#pragma unroll
    for (int tq = 0; tq < 6; ++tq) {
        const int sl = (wid_u + tq * 4) * 8 + (lane >> 3);
        const int row = sl / 66, col = sl - row * 66;
        srcq[tq] = xtp + ((size_t)(b * XPD + yb + row) * XPD + col) * 512 +
                   (up ^ (col & 7)) * 8;
    }
    const int col6 = 60 + (lane >> 3);   // partial: slices 192..197 = row 2, col 60..65
    const unsigned short* src6 =
        xtp + ((size_t)(b * XPD + yb + 2) * XPD + col6) * 512 + (up ^ (col6 & 7)) * 8;

    // swizzled B ds byte-voffsets (col = l15+kx, phys unit = (ks*4+l4) ^ (col&7))
    int vB[3][2];
#pragma unroll
    for (int kx = 0; kx < 3; ++kx)
#pragma unroll
        for (int ks = 0; ks < 2; ++ks)
            vB[kx][ks] = (l15 + kx) * 128 + (((ks * 4 + l4) ^ ((l15 + kx) & 7)) * 16);

    f32x4 acc[4][4];
#pragma unroll
    for (int mi = 0; mi < 4; ++mi)
#pragma unroll
        for (int j = 0; j < 4; ++j) acc[mi][j] = (f32x4){0.f, 0.f, 0.f, 0.f};

    short8 af[3][4];   // 2-deep A prefetch rotation, static indices only

    // A frag addr (shorts): aP + G*16384 + mi*512, G = ic*18 + s (s: ks = s/9, tap = s%9)
    const unsigned short* aP = wpk + (size_t)g0 * 512 + lane * 8;

#define STAGE(bufp, icq)                                                                  \
    do {                                                                                  \
        unsigned short* dbase = xs + (bufp) * BUFSH + wid_u * 512;                        \
        _Pragma("unroll") for (int tq = 0; tq < 6; ++tq)                                  \
            gll16(srcq[tq] + (size_t)(icq) * 64, dbase + tq * 2048);                      \
        if (wid_u == 0 && lane < 48)                                                      \
            gll16(src6 + (size_t)(icq) * 64, xs + (bufp) * BUFSH + 12288);                \
    } while (0)

#define PHX(s)                                                                            \
    do {                                                                                  \
        short8 bfr[4];                                                                    \
        const char* bp = (const char*)xs + cbase +                                        \
                         (((s) % 9) / 3) * ROWB + vB[((s) % 9) % 3][(s) / 9];             \
        _Pragma("unroll") for (int j = 0; j < 4; ++j)                                     \
            bfr[j] = *(const short8*)(bp + j * 2048);                                     \
        {                                                                                 \
            const unsigned short* pA = aPic + (size_t)((s) + 2) * 16384;                  \
            _Pragma("unroll") for (int mi = 0; mi < 4; ++mi)                              \
                af[((s) + 2) % 3][mi] = *(const short8*)(pA + mi * 512);                  \
        }                                                                                 \
        if ((s) == 0 && ic < 7) STAGE((ic + 1) & 1, ic + 1);                              \
        __builtin_amdgcn_s_barrier();                                                     \
        asm volatile("s_waitcnt lgkmcnt(0)" ::: "memory");                                \
        __builtin_amdgcn_s_setprio(1);                                                    \
        _Pragma("unroll") for (int mi = 0; mi < 4; ++mi)                                  \
            _Pragma("unroll") for (int j = 0; j < 4; ++j)                                 \
                acc[mi][j] = __builtin_amdgcn_mfma_f32_16x16x32_bf16(                     \
                    af[(s) % 3][mi], bfr[j], acc[mi][j], 0, 0, 0);                        \
        __builtin_amdgcn_s_setprio(0);                                                    \
        if ((s) == 17) asm volatile("s_waitcnt vmcnt(8)" ::: "memory");                   \
        __builtin_amdgcn_s_barrier();                                                     \
    } while (0)

    // prologue: prefetch A sets G=0,1, then stage buffer 0, full drain once
    af[0][0] = *(const short8*)(aP + 0 * 512);
    af[0][1] = *(const short8*)(aP + 1 * 512);
    af[0][2] = *(const short8*)(aP + 2 * 512);
    af[0][3] = *(const short8*)(aP + 3 * 512);
    {
        const unsigned short* p1 = aP + 16384;
        af[1][0] = *(const short8*)(p1 + 0 * 512);
        af[1][1] = *(const short8*)(p1 + 1 * 512);
        af[1][2] = *(const short8*)(p1 + 2 * 512);
        af[1][3] = *(const short8*)(p1 + 3 * 512);
    }
    STAGE(0, 0);
    __syncthreads();

#pragma unroll 1
    for (int ic = 0; ic < 8; ++ic) {
        const unsigned short* aPic = aP + (size_t)ic * (18 * 16384);
        const int cbase = (ic & 1) * (BUFSH * 2);   // bytes
        PHX(0);  PHX(1);  PHX(2);  PHX(3);  PHX(4);  PHX(5);
        PHX(6);  PHX(7);  PHX(8);  PHX(9);  PHX(10); PHX(11);
        PHX(12); PHX(13); PHX(14); PHX(15); PHX(16); PHX(17);
    }

    // epilogue: D-frag col = l15 (px), row = l4*4 + rr (o); scale by sigma_inv, add bias
#pragma unroll
    for (int mi = 0; mi < 4; ++mi) {
        const int obase = ob * 256 + og * 64 + mi * 16 + l4 * 4;
#pragma unroll
        for (int rr = 0; rr < 4; ++rr) {
            const int o = obase + rr;
            const float sv = siginv[b * COUT + o];
            const float bv = bias[o];
            float* orow = out + (((size_t)(b * COUT + o) * HH + yb) << 6);
#pragma unroll
            for (int j = 0; j < 4; ++j) {
                orow[j * 16 + l15] = acc[mi][j][rr] * sv + bv;
            }
        }
    }
#undef STAGE
#undef PHX
}

extern "C" void kernel_launch(void* const* d_in, const int* in_sizes, int n_in,
                              void* d_out, int out_size, void* d_ws, size_t ws_size,
                              hipStream_t stream) {
    const float* x      = (const float*)d_in[0];
    const float* style  = (const float*)d_in[1];
    const float* weight = (const float*)d_in[2];
    const float* bias   = (const float*)d_in[3];
    float* out = (float*)d_out;

    unsigned short* wpk = (unsigned short*)d_ws;                  // 16*9*32*64*8 shorts (4.72 MB)
    unsigned short* xtp = wpk + (size_t)2359296;                  // 8*66*66*512 shorts (35.7 MB)
    float* siginv = (float*)(xtp + (size_t)BB * XPD * XPD * 512); // 8*512 f32

    zring_kernel<<<520, 256, 0, stream>>>(xtp);
    xpose_kernel<<<dim3(16, HH, BB), 256, 0, stream>>>(x, style, xtp);
    wprep_kernel<<<COUT, 256, 0, stream>>>(weight, style, wpk, siginv);
    conv_kernel<<<1024, 256, 0, stream>>>(wpk, xtp, siginv, bias, out);
}

// Round 15
// 160.167 us; speedup vs baseline: 1.0481x; 1.0481x over previous
//
#include <hip/hip_runtime.h>

#define CIN 512
#define COUT 512
#define HH 64
#define WW 64
#define BB 8
#define KTOT 4608   // 512*9

#define XPD 66                // padded spatial dim: index = coord+1, coord in -1..64
#define BUFSH (3 * 66 * 64)   // 12672 shorts per LDS buffer (3 rows x 66 slices x 64 ch)
#define ROWB (66 * 128)       // 8448 bytes per LDS input row

typedef __attribute__((ext_vector_type(8))) short short8;
typedef __attribute__((ext_vector_type(4))) float f32x4;

__device__ inline unsigned short f2bf(float f) {
    unsigned int u = __float_as_uint(f);
    u += 0x7FFFu + ((u >> 16) & 1u);   // round-to-nearest-even
    return (unsigned short)(u >> 16);
}

__device__ inline void gll16(const void* g, void* l) {
    __builtin_amdgcn_global_load_lds(
        (const __attribute__((address_space(1))) unsigned int*)g,
        (__attribute__((address_space(3))) unsigned int*)l, 16, 0, 0);
}

// ------- Phase 0: x [b][i][y][x] fp32 * (1+style[b][i]) -> XTP [b][y+1][x+1][i] bf16 -------
// Halo ring fused (replaces the old zring kernel): every block zeroes its row's
// col-0/col-65 slices for its ch chunk; y==0 / y==63 blocks zero rows 0 / 65.
__global__ __launch_bounds__(256) void xpose_kernel(const float* __restrict__ x,
                                                    const float* __restrict__ style,
                                                    unsigned short* __restrict__ xtp) {
    __shared__ float tile[32 * 65];
    __shared__ float sst[32];
    const int ic = blockIdx.x;   // 16 groups of 32 channels
    const int y  = blockIdx.y;
    const int b  = blockIdx.z;
    const int t  = threadIdx.x;
    const short8 z8 = (short8){0, 0, 0, 0, 0, 0, 0, 0};
    if (t < 32) sst[t] = style[b * CIN + ic * 32 + t] + 1.0f;
    // left/right halo of this padded row (col 0 and 65), 32 ch = 4 short8 per side
    if (t < 8) {
        const int side = t >> 2, u = t & 3;
        *(short8*)(xtp + ((size_t)(b * XPD + y + 1) * XPD + (side ? 65 : 0)) * 512 +
                   ic * 32 + u * 8) = z8;
    }
    // top / bottom padded rows (row 0 for y==0 blocks, row 65 for y==63 blocks)
    if (y == 0 || y == 63) {
        const int prow = (y == 0) ? 0 : 65;
        for (int e = t; e < 264; e += 256) {   // 66 cols x 4 short8
            const int col = e >> 2, u = e & 3;
            *(short8*)(xtp + ((size_t)(b * XPD + prow) * XPD + col) * 512 +
                       ic * 32 + u * 8) = z8;
        }
    }
#pragma unroll
    for (int it = 0; it < 2; ++it) {
        const int m  = it * 256 + t;        // 0..511 float4 loads
        const int ii = m >> 4, xq = m & 15;
        const float4 v = ((const float4*)x)[((size_t)(b * CIN + ic * 32 + ii) * HH + y) * 16 + xq];
        float* tp = &tile[ii * 65 + xq * 4];
        tp[0] = v.x; tp[1] = v.y; tp[2] = v.z; tp[3] = v.w;
    }
    __syncthreads();
    const int xx = t >> 2, ii8 = t & 3;     // 64 cols x 4 ch-octets
    short8 v8;
#pragma unroll
    for (int k = 0; k < 8; ++k)
        v8[k] = (short)f2bf(tile[(ii8 * 8 + k) * 65 + xx] * sst[ii8 * 8 + k]);
    *(short8*)(xtp + ((size_t)(b * XPD + y + 1) * XPD + (xx + 1)) * 512 + ic * 32 + ii8 * 8) = v8;
}

// ------- Phase 1 (fused): frag-pack w*c AND sigma_inv[b][o], one weight-row pass -------
// Wpk flat: (((c*9 + tap)*32 + g)*64 + lane)*8 + e ; lane = l4*16+l15 holds
//   W[o = g*16+l15][i = c*32 + l4*8 + e],  c = 16 chunks of 32 input ch.
__global__ __launch_bounds__(256) void wprep_kernel(const float* __restrict__ weight,
                                                    const float* __restrict__ style,
                                                    unsigned short* __restrict__ wpk,
                                                    float* __restrict__ siginv) {
    __shared__ float q[KTOT];
    __shared__ float sred[4][8];
    const int o = blockIdx.x;
    const int t = threadIdx.x;
    const float* wrow = weight + (size_t)o * KTOT;   // e = i*9+tap
    const float cst = 1.0f / sqrtf((float)KTOT);
#pragma unroll
    for (int it = 0; it < 18; ++it) {
        int e = it * 256 + t;
        q[e] = wrow[e] * cst;
    }
    __syncthreads();
    float acc[8] = {0.f, 0.f, 0.f, 0.f, 0.f, 0.f, 0.f, 0.f};
#pragma unroll
    for (int ii = 0; ii < 2; ++ii) {
        const int i = t * 2 + ii;
        float wsq = 0.f;
#pragma unroll
        for (int tap = 0; tap < 9; ++tap) {
            float v = q[i * 9 + tap];
            wsq += v * v;
        }
#pragma unroll
        for (int b = 0; b < 8; ++b) {
            float s = style[b * CIN + i] + 1.0f;
            acc[b] += wsq * s * s;
        }
    }
#pragma unroll
    for (int b = 0; b < 8; ++b) {
        float v = acc[b];
#pragma unroll
        for (int off = 32; off > 0; off >>= 1) v += __shfl_down(v, off, 64);
        if ((t & 63) == 0) sred[t >> 6][b] = v;
    }
    __syncthreads();
    if (t < 8) {
        const float S = sred[0][t] + sred[1][t] + sred[2][t] + sred[3][t];
        siginv[t * COUT + o] = rsqrtf(S + 1e-8f);
    }
    const int g = o >> 4, l15 = o & 15;
    for (int m = t; m < 576; m += 256) {   // m -> (c, tap, l4)
        int c   = m / 36;
        int rem = m - c * 36;
        int tap = rem >> 2;
        int l4  = rem & 3;
        short8 v;
#pragma unroll
        for (int e = 0; e < 8; ++e)
            v[e] = (short)f2bf(q[(c * 32 + l4 * 8 + e) * 9 + tap]);
        *(short8*)(wpk + ((((size_t)c * 9 + tap) * 32 + g) * 64 + l4 * 16 + l15) * 8) = v;
    }
}

// ---------------- Phase 2: implicit-GEMM conv (r8/r13, proven ~135 us) ----------------
// block: 256 thr = 4 waves; tile 256 o x 1 output row x 64 px; 3 blocks/CU.
// wave og = wid: 64 o x 64 px -> acc[4][4] (64 AGPR).
// A-path: 2-deep static prefetch rotation af[3]; G = ic*18+s linear in wpk.
// X: 3 input rows x 66 slices x 64 ch per buffer, XOR-8 swizzle (conflict-free).
// Structural ceiling note: 7 variants (r5-r14) all pin MfmaUtil at 47-55%; the
// free-running-body + drain-barrier structure caps the matrix pipe here (m233).
__global__ __launch_bounds__(256, 3) void conv_kernel(const unsigned short* __restrict__ wpk,
                                                      const unsigned short* __restrict__ xtp,
                                                      const float* __restrict__ siginv,
                                                      const float* __restrict__ bias,
                                                      float* __restrict__ out) {
    __shared__ __align__(16) unsigned short xs[2 * BUFSH];   // 50688 B
    // XCD-aware decode: XCD k = bid&7 owns ob = k&1 (2.36 MB weight half, L2-hot)
    const int bid = blockIdx.x;
    const int k  = bid & 7;
    const int t  = bid >> 3;            // 0..127
    const int ob = k & 1;
    const int b  = (k >> 1) * 2 + (t >> 6);
    const int yb = t & 63;              // output row

    const int tid  = threadIdx.x;
    const int lane = tid & 63;
    const int wid_u = __builtin_amdgcn_readfirstlane(tid >> 6);   // wave-uniform -> SGPR
    const int l15 = lane & 15, l4 = lane >> 4;
    const int og = wid_u;               // 0..3, 64 o each
    const int g0 = ob * 16 + og * 4;    // o-frag base (frags of 16 o), scalar

    // ---- staging precompute: slices 0..197 (row = sl/66, col = sl%66), 128B each.
    const int up = lane & 7;
    const unsigned short* srcq[6];
#pragma unroll
    for (int tq = 0; tq < 6; ++tq) {
        const int sl = (wid_u + tq * 4) * 8 + (lane >> 3);
        const int row = sl / 66, col = sl - row * 66;
        srcq[tq] = xtp + ((size_t)(b * XPD + yb + row) * XPD + col) * 512 +
                   (up ^ (col & 7)) * 8;
    }
    const int col6 = 60 + (lane >> 3);   // partial: slices 192..197 = row 2, col 60..65
    const unsigned short* src6 =
        xtp + ((size_t)(b * XPD + yb + 2) * XPD + col6) * 512 + (up ^ (col6 & 7)) * 8;

    // swizzled B ds byte-voffsets (col = l15+kx, phys unit = (ks*4+l4) ^ (col&7))
    int vB[3][2];
#pragma unroll
    for (int kx = 0; kx < 3; ++kx)
#pragma unroll
        for (int ks = 0; ks < 2; ++ks)
            vB[kx][ks] = (l15 + kx) * 128 + (((ks * 4 + l4) ^ ((l15 + kx) & 7)) * 16);

    f32x4 acc[4][4];
#pragma unroll
    for (int mi = 0; mi < 4; ++mi)
#pragma unroll
        for (int j = 0; j < 4; ++j) acc[mi][j] = (f32x4){0.f, 0.f, 0.f, 0.f};

    short8 af[3][4];   // 2-deep prefetch rotation, static indices only

    // A frag addr (shorts): aP + G*16384 + mi*512, G = ic*18 + s (s: ks = s/9, tap = s%9)
    const unsigned short* aP = wpk + (size_t)g0 * 512 + lane * 8;

#define STAGE(bufp, icq)                                                                  \
    do {                                                                                  \
        unsigned short* dbase = xs + (bufp) * BUFSH + wid_u * 512;                        \
        _Pragma("unroll") for (int tq = 0; tq < 6; ++tq)                                  \
            gll16(srcq[tq] + (size_t)(icq) * 64, dbase + tq * 2048);                      \
        if (wid_u == 0 && lane < 48)                                                      \
            gll16(src6 + (size_t)(icq) * 64, xs + (bufp) * BUFSH + 12288);                \
    } while (0)

#define PHASE(s, aPic, cbase)                                                             \
    do {                                                                                  \
        const unsigned short* pA = (aPic) + (size_t)((s) + 2) * 16384;                    \
        _Pragma("unroll") for (int mi = 0; mi < 4; ++mi)                                  \
            af[((s) + 2) % 3][mi] = *(const short8*)(pA + mi * 512);                      \
        short8 bfr[4];                                                                    \
        const char* bp = (const char*)xs + (cbase) +                                      \
                         (((s) % 9) / 3) * ROWB + vB[((s) % 9) % 3][(s) / 9];             \
        _Pragma("unroll") for (int j = 0; j < 4; ++j)                                     \
            bfr[j] = *(const short8*)(bp + j * 2048);                                     \
        __builtin_amdgcn_s_setprio(1);                                                    \
        _Pragma("unroll") for (int mi = 0; mi < 4; ++mi)                                  \
            _Pragma("unroll") for (int j = 0; j < 4; ++j)                                 \
                acc[mi][j] = __builtin_amdgcn_mfma_f32_16x16x32_bf16(                     \
                    af[(s) % 3][mi], bfr[j], acc[mi][j], 0, 0, 0);                        \
        __builtin_amdgcn_s_setprio(0);                                                    \
    } while (0)

    // prologue: prefetch A sets G=0,1, then stage buffer 0
    af[0][0] = *(const short8*)(aP + 0 * 512);
    af[0][1] = *(const short8*)(aP + 1 * 512);
    af[0][2] = *(const short8*)(aP + 2 * 512);
    af[0][3] = *(const short8*)(aP + 3 * 512);
    {
        const unsigned short* p1 = aP + 16384;
        af[1][0] = *(const short8*)(p1 + 0 * 512);
        af[1][1] = *(const short8*)(p1 + 1 * 512);
        af[1][2] = *(const short8*)(p1 + 2 * 512);
        af[1][3] = *(const short8*)(p1 + 3 * 512);
    }
    STAGE(0, 0);
    __syncthreads();

#pragma unroll 1
    for (int ic = 0; ic < 8; ++ic) {
        if (ic < 7) STAGE((ic + 1) & 1, ic + 1);
        const unsigned short* aPic = aP + (size_t)ic * (18 * 16384);
        const int cbase = (ic & 1) * (BUFSH * 2);   // bytes
#pragma unroll
        for (int s = 0; s < 18; ++s) {
            PHASE(s, aPic, cbase);   // s=16,17 prefetch next ic's sets 0,1 (linear G)
        }
        __syncthreads();
    }

    // epilogue: D-frag col = l15 (px), row = l4*4 + rr (o); scale by sigma_inv, add bias
#pragma unroll
    for (int mi = 0; mi < 4; ++mi) {
        const int obase = ob * 256 + og * 64 + mi * 16 + l4 * 4;
#pragma unroll
        for (int rr = 0; rr < 4; ++rr) {
            const int o = obase + rr;
            const float sv = siginv[b * COUT + o];
            const float bv = bias[o];
            float* orow = out + (((size_t)(b * COUT + o) * HH + yb) << 6);
#pragma unroll
            for (int j = 0; j < 4; ++j) {
                orow[j * 16 + l15] = acc[mi][j][rr] * sv + bv;
            }
        }
    }
#undef STAGE
#undef PHASE
}

extern "C" void kernel_launch(void* const* d_in, const int* in_sizes, int n_in,
                              void* d_out, int out_size, void* d_ws, size_t ws_size,
                              hipStream_t stream) {
    const float* x      = (const float*)d_in[0];
    const float* style  = (const float*)d_in[1];
    const float* weight = (const float*)d_in[2];
    const float* bias   = (const float*)d_in[3];
    float* out = (float*)d_out;

    unsigned short* wpk = (unsigned short*)d_ws;                  // 16*9*32*64*8 shorts (4.72 MB)
    unsigned short* xtp = wpk + (size_t)2359296;                  // 8*66*66*512 shorts (35.7 MB)
    float* siginv = (float*)(xtp + (size_t)BB * XPD * XPD * 512); // 8*512 f32

    xpose_kernel<<<dim3(16, HH, BB), 256, 0, stream>>>(x, style, xtp);
    wprep_kernel<<<COUT, 256, 0, stream>>>(weight, style, wpk, siginv);
    conv_kernel<<<1024, 256, 0, stream>>>(wpk, xtp, siginv, bias, out);
}